// Round 9
// baseline (138.690 us; speedup 1.0000x reference)
//
#include <hip/hip_runtime.h>

// Guided blur (multichannel guided filter), B=8, C=Cp=3, H=W=512, k=5, eps=1e-4.
// SINGLE fused kernel, LDS-free, barrier-free, 16-lane-row DPP horizontal taps,
// guidance-from-ring, 1-row stage pipeline (r16 structure).
// r17 change (distance-2 prefetch ring -> guaranteed vmcnt latency coverage):
//   - r16 post-mortem: stage2-lag reorder EXACTLY neutral (60.2us, VALUBusy 60.5%).
//     r13's 5-row single-block body already let the scheduler interleave across rows
//     -> source-level ILP exhausted. Hypothesis set now: {vmcnt exposure from
//     load-issue sinking, DPP issue-rate/hazard, I-fetch}.
//   - vmcnt-exposure theory: compiler sinks the 6 global_loads toward their waitcnt
//     (shortens P's live range); distance-1 then exposes ~200-900cy L2/HBM latency at
//     the TOP of every row. Both co-resident waves run identical code in lockstep ->
//     stall together, can't cover each other. Explains: occupancy-invariance (r9/r11),
//     load-REMOVAL neutrality (r13: remaining 6 loads' latency intact -> exactly flat),
//     reorder neutrality (r16: loads didn't move).
//   - Fix: P[2][6] ring, constexpr parity slot s=rr&1. Consume P[s] (row rr, loaded at
//     rr-2), then load row rr+2 into P[s]. Even if issue sinks to row-end, wait at
//     rr+2's top has >= 1 full row (~1800cy) coverage. 5 is odd -> parity not constant
//     per ring slot -> steady loop = 10-row body x3 (rr=10..39); warm-up rr=0..9
//     unrolled. +6 VGPR.
//   Compile-shape lessons (this session):
//     r5: runtime ring idx -> PromoteAlloca-to-LDS -> 40us LDS-pipe serialization
//     r7: f2 ext-vector arrays in state struct -> failed SROA -> scratch spill (159us)
//     r8: __launch_bounds__(128,4) -> forced 64-VGPR cap -> 440MB spill traffic (213us)
//     r10: wave_shl1 DPP (ctrl 0x130) -> VALUBusy 21%, 160us
//     r14: ds_bpermute hsum5 chains at 1.25 waves/SIMD -> latency-bound, 80us
//     r15: runtime-branch rolled body -> CFG-split scheduling collapse, 91us
//     r16: stage2-lag reorder -> neutral (scheduler already interleaved rows)
//   Proven safe form: scalar floats, constexpr ring indices, block=64,
//   __launch_bounds__(64,2), SR=32 geometry, big single-block trip bodies.
// No d_ws usage.

namespace {

constexpr int BN = 8;
constexpr int HH = 512;
constexpr int WW = 512;
constexpr int CSZ = HH * WW;
constexpr float GEPS = 1e-4f;
constexpr int SEGW = 8;             // output cols per 16-lane segment
constexpr int OUTW = 4 * SEGW;      // 32 output cols per wave
constexpr int SR   = 32;            // output rows per wave strip (reads SR+8 raw rows)

__device__ __forceinline__ int refl(int i, int n) {
    // jnp.pad reflect: -1 -> 1, -2 -> 2, n -> n-2, n+1 -> n-3
    if (i < 0) i = -i;
    if (i >= n) i = 2 * n - 2 - i;
    return i;
}

// DPP row_shl:N within each 16-lane row: lane u receives lane u+N (0 past row end).
template <int N>
__device__ __forceinline__ float shlN(float v) {
    return __builtin_bit_cast(float,
        __builtin_amdgcn_update_dpp(0, __builtin_bit_cast(int, v),
                                    0x100 + N, 0xF, 0xF, true));
}
// row-local lane u gets v[u]+v[u+1]+v[u+2]+v[u+3]+v[u+4]; valid for u <= 11.
__device__ __forceinline__ float hsum5(float v) {
    float t = v + shlN<1>(v);
    float q = t + shlN<2>(t);
    return q + shlN<4>(v);
}

struct St {
    float P[2][6];     // distance-2 prefetch ring (slot = rr & 1)
    float V1[21];      // stage-1 vertical window sums (21 stat channels)
    float r1[5][6];    // last 5 raw rows (6 channels)
    float V2[12];      // stage-2 vertical sums of hsum'd a,b
    float r2[5][12];   // last 5 hsum'd a,b rows
    float A[12];       // pipeline reg: a00..a22,b0..b2 from PREVIOUS iteration's solve
};

struct Ctx {
    const float *g0, *g1, *g2, *p0, *p1, *p2;  // channel base pointers
    float *o0, *o1, *o2;
    int yb, xr, xs;
    bool wr;
};

// Stage 2 of iteration rr: consumes st.A = solve(rr-1). Runs BEFORE stage1<I>
// overwrites ring slot I (which holds raw row rr-5 = the output row's guidance).
template <int I, bool V2SUB, bool OUT>
__device__ __forceinline__ void stage2(St& st, const Ctx& cx, int rr) {
    float hv[12];
    hv[0] = hsum5(st.A[0]); hv[1]  = hsum5(st.A[1]); hv[2]  = hsum5(st.A[2]);
    hv[3] = hsum5(st.A[3]); hv[4]  = hsum5(st.A[4]); hv[5]  = hsum5(st.A[5]);
    hv[6] = hsum5(st.A[6]); hv[7]  = hsum5(st.A[7]); hv[8]  = hsum5(st.A[8]);
    hv[9] = hsum5(st.A[9]); hv[10] = hsum5(st.A[10]); hv[11] = hsum5(st.A[11]);

#pragma unroll
    for (int c = 0; c < 12; ++c) {
        st.V2[c] += hv[c];
        if constexpr (V2SUB) st.V2[c] -= st.r2[I][c];  // read old before overwrite
        st.r2[I][c] = hv[c];
    }

    if constexpr (OUT) {
        // output row yo = yb + rr - 9 == raw row rr-5 (interior, refl identity),
        // live in ring slot I (not yet overwritten this iteration). Needed col
        // xbase+l+2 = raw col of lane l+4 -> row_shl:4 within the 16-lane segment;
        // lanes l>=8 get garbage/0 but have wr==false.
        float gg0 = shlN<4>(st.r1[I][0]);
        float gg1 = shlN<4>(st.r1[I][1]);
        float gg2 = shlN<4>(st.r1[I][2]);
        const int oOff = (cx.yb + rr - 9) * WW + cx.xs;
        // mean = V2 / 25
        float M[12];
#pragma unroll
        for (int c = 0; c < 12; ++c) M[c] = st.V2[c] * 0.04f;
        float o0 = gg0 * M[0] + gg1 * M[3] + gg2 * M[6] + M[9];
        float o1 = gg0 * M[1] + gg1 * M[4] + gg2 * M[7] + M[10];
        float o2 = gg0 * M[2] + gg1 * M[5] + gg2 * M[8] + M[11];
        if (cx.wr) {
            cx.o0[oOff] = o0;
            cx.o1[oOff] = o1;
            cx.o2[oOff] = o2;
        }
    }
}

// Stage 1 of iteration rr: raw-row consume + V1 roll + (solve -> st.A).
// Raw ring slot = constexpr I (rr%5 == I); prefetch slot = constexpr PAR (rr&1).
// Consumes P[PAR] (row rr, loaded 2 iterations ago); if PF, loads row rr+2 into P[PAR].
template <int I, int PAR, bool SUB1, bool SOLVE, bool PF>
__device__ __forceinline__ void stage1(St& st, const Ctx& cx, int rr) {
    // capture current values from prefetch slot BEFORE overwriting it
    float c0 = st.P[PAR][0], c1 = st.P[PAR][1], c2 = st.P[PAR][2];
    float c3 = st.P[PAR][3], c4 = st.P[PAR][4], c5 = st.P[PAR][5];

    if constexpr (PF) {   // row rr+2; first use is 2 iterations from now.
        const int yn = refl(cx.yb - 4 + rr + 2, HH);  // worst case 517 -> 505, in-bounds
        const int offn = yn * WW + cx.xr;
        st.P[PAR][0] = cx.g0[offn]; st.P[PAR][1] = cx.g1[offn]; st.P[PAR][2] = cx.g2[offn];
        st.P[PAR][3] = cx.p0[offn]; st.P[PAR][4] = cx.p1[offn]; st.P[PAR][5] = cx.p2[offn];
    }

    // add current raw row
    st.V1[0] += c0; st.V1[1] += c1; st.V1[2] += c2;
    st.V1[3] += c3; st.V1[4] += c4; st.V1[5] += c5;
    st.V1[6]  += c0 * c0; st.V1[7]  += c0 * c1; st.V1[8]  += c0 * c2;
    st.V1[9]  += c1 * c1; st.V1[10] += c1 * c2; st.V1[11] += c2 * c2;
    st.V1[12] += c0 * c3; st.V1[13] += c0 * c4; st.V1[14] += c0 * c5;
    st.V1[15] += c1 * c3; st.V1[16] += c1 * c4; st.V1[17] += c1 * c5;
    st.V1[18] += c2 * c3; st.V1[19] += c2 * c4; st.V1[20] += c2 * c5;

    if constexpr (SUB1) {   // drop raw row rr-5 (same constexpr slot I)
        float o0 = st.r1[I][0], o1 = st.r1[I][1], o2 = st.r1[I][2];
        float o3 = st.r1[I][3], o4 = st.r1[I][4], o5 = st.r1[I][5];
        st.V1[0] -= o0; st.V1[1] -= o1; st.V1[2] -= o2;
        st.V1[3] -= o3; st.V1[4] -= o4; st.V1[5] -= o5;
        st.V1[6]  -= o0 * o0; st.V1[7]  -= o0 * o1; st.V1[8]  -= o0 * o2;
        st.V1[9]  -= o1 * o1; st.V1[10] -= o1 * o2; st.V1[11] -= o2 * o2;
        st.V1[12] -= o0 * o3; st.V1[13] -= o0 * o4; st.V1[14] -= o0 * o5;
        st.V1[15] -= o1 * o3; st.V1[16] -= o1 * o4; st.V1[17] -= o1 * o5;
        st.V1[18] -= o2 * o3; st.V1[19] -= o2 * o4; st.V1[20] -= o2 * o5;
    }
    st.r1[I][0] = c0; st.r1[I][1] = c1; st.r1[I][2] = c2;
    st.r1[I][3] = c3; st.r1[I][4] = c4; st.r1[I][5] = c5;

    if constexpr (SOLVE) {
        // ---- stage 1 finalize: a-row at y = yb + rr - 6, a-col xbase+l ----
        float S[21];
#pragma unroll
        for (int c = 0; c < 21; ++c) S[c] = hsum5(st.V1[c]);

        const float nrm = 0.04f;  // 1/25
        float mI0 = S[0] * nrm, mI1 = S[1] * nrm, mI2 = S[2] * nrm;
        float mP0 = S[3] * nrm, mP1 = S[4] * nrm, mP2 = S[5] * nrm;
        float v00 = S[6]  * nrm - mI0 * mI0 + GEPS;
        float v01 = S[7]  * nrm - mI0 * mI1;
        float v02 = S[8]  * nrm - mI0 * mI2;
        float v11 = S[9]  * nrm - mI1 * mI1 + GEPS;
        float v12 = S[10] * nrm - mI1 * mI2;
        float v22 = S[11] * nrm - mI2 * mI2 + GEPS;
        float c00 = S[12] * nrm - mI0 * mP0;
        float c01 = S[13] * nrm - mI0 * mP1;
        float c02 = S[14] * nrm - mI0 * mP2;
        float c10 = S[15] * nrm - mI1 * mP0;
        float c11 = S[16] * nrm - mI1 * mP1;
        float c12 = S[17] * nrm - mI1 * mP2;
        float c20 = S[18] * nrm - mI2 * mP0;
        float c21 = S[19] * nrm - mI2 * mP1;
        float c22 = S[20] * nrm - mI2 * mP2;
        // symmetric 3x3 inverse via adjugate (A PD: PSD + eps*I)
        float i00 = v11 * v22 - v12 * v12;
        float i01 = v02 * v12 - v01 * v22;
        float i02 = v01 * v12 - v02 * v11;
        float i11 = v00 * v22 - v02 * v02;
        float i12 = v01 * v02 - v00 * v12;
        float i22 = v00 * v11 - v01 * v01;
        float det = v00 * i00 + v01 * i01 + v02 * i02;
        float rd  = __builtin_amdgcn_rcpf(det);   // ~1e-7 rel err, fine vs 0.019 threshold
        st.A[0]  = (i00 * c00 + i01 * c10 + i02 * c20) * rd;   // a00
        st.A[1]  = (i00 * c01 + i01 * c11 + i02 * c21) * rd;   // a01
        st.A[2]  = (i00 * c02 + i01 * c12 + i02 * c22) * rd;   // a02
        st.A[3]  = (i01 * c00 + i11 * c10 + i12 * c20) * rd;   // a10
        st.A[4]  = (i01 * c01 + i11 * c11 + i12 * c21) * rd;   // a11
        st.A[5]  = (i01 * c02 + i11 * c12 + i12 * c22) * rd;   // a12
        st.A[6]  = (i02 * c00 + i12 * c10 + i22 * c20) * rd;   // a20
        st.A[7]  = (i02 * c01 + i12 * c11 + i22 * c21) * rd;   // a21
        st.A[8]  = (i02 * c02 + i12 * c12 + i22 * c22) * rd;   // a22
        st.A[9]  = mP0 - (st.A[0] * mI0 + st.A[3] * mI1 + st.A[6] * mI2);  // b0
        st.A[10] = mP1 - (st.A[1] * mI0 + st.A[4] * mI1 + st.A[7] * mI2);  // b1
        st.A[11] = mP2 - (st.A[2] * mI0 + st.A[5] * mI1 + st.A[8] * mI2);  // b2
    }
}

__global__ __launch_bounds__(64, 2) void fused_kernel(
        const float* __restrict__ g, const float* __restrict__ p,
        float* __restrict__ out) {
    const int lane = threadIdx.x;       // 64 threads = 1 wave
    const int l    = lane & 15;
    const int seg  = lane >> 4;
    const int XO   = blockIdx.x * OUTW;
    const int bb   = blockIdx.z;

    const int xbase = XO + seg * SEGW - 2;          // a-col of row-local lane 0
    const int xrq   = xbase + l - 2;                // raw read col (pre-reflect)
    const int xo    = xbase + l + 2;                // output col (valid l < SEGW)

    Ctx cx;
    cx.g0 = g + (size_t)bb * 3 * CSZ; cx.g1 = cx.g0 + CSZ; cx.g2 = cx.g0 + 2 * CSZ;
    cx.p0 = p + (size_t)bb * 3 * CSZ; cx.p1 = cx.p0 + CSZ; cx.p2 = cx.p0 + 2 * CSZ;
    cx.o0 = out + (size_t)bb * 3 * CSZ; cx.o1 = cx.o0 + CSZ; cx.o2 = cx.o0 + 2 * CSZ;
    cx.yb = blockIdx.y * SR;
    cx.xr = refl(xrq, WW);
    cx.xs = (xo < WW) ? xo : (WW - 1);
    cx.wr = (l < SEGW);                             // xo < 512 guaranteed for l < SEGW

    St st;
#pragma unroll
    for (int i = 0; i < 21; ++i) st.V1[i] = 0.f;
#pragma unroll
    for (int i = 0; i < 12; ++i) st.V2[i] = 0.f;
    // A first read at rr=5 stage2 (written rr=4 solve); r1/r2 write-before-read.

    // prime the prefetch ring: row 0 -> P[0], row 1 -> P[1]
    {
        const int y0 = refl(cx.yb - 4, HH);
        const int off0 = y0 * WW + cx.xr;
        st.P[0][0] = cx.g0[off0]; st.P[0][1] = cx.g1[off0]; st.P[0][2] = cx.g2[off0];
        st.P[0][3] = cx.p0[off0]; st.P[0][4] = cx.p1[off0]; st.P[0][5] = cx.p2[off0];
        const int y1 = refl(cx.yb - 3, HH);
        const int off1 = y1 * WW + cx.xr;
        st.P[1][0] = cx.g0[off1]; st.P[1][1] = cx.g1[off1]; st.P[1][2] = cx.g2[off1];
        st.P[1][3] = cx.p0[off1]; st.P[1][4] = cx.p1[off1]; st.P[1][5] = cx.p2[off1];
    }

    // 41 iterations: rr=0..39 consume raw rows; rr=40 = stage2 epilogue.
    // stage2(rr) processes solve(rr-1); outputs at rr=9..40 -> rows yb..yb+31.
    // warm-up rr=0..9 (PAR = rr&1): first solve rr=4, stage2 on from rr=5, OUT from rr=9
    stage1<0, 0, false, false, true>(st, cx, 0);
    stage1<1, 1, false, false, true>(st, cx, 1);
    stage1<2, 0, false, false, true>(st, cx, 2);
    stage1<3, 1, false, false, true>(st, cx, 3);
    stage1<4, 0, false, true,  true>(st, cx, 4);
    stage2<0, false, false>(st, cx, 5); stage1<0, 1, true, true, true>(st, cx, 5);
    stage2<1, false, false>(st, cx, 6); stage1<1, 0, true, true, true>(st, cx, 6);
    stage2<2, false, false>(st, cx, 7); stage1<2, 1, true, true, true>(st, cx, 7);
    stage2<3, false, false>(st, cx, 8); stage1<3, 0, true, true, true>(st, cx, 8);
    stage2<4, false, true >(st, cx, 9); stage1<4, 1, true, true, true>(st, cx, 9);
    // steady: rr=10..39 as 3 x 10-row body (10 = lcm(5,2): ring idx AND parity fixed
    // per position). PF at rr=38/39 loads rows 40/41 -> refl 506/505, in-bounds, unused.
#pragma unroll 1
    for (int m = 1; m <= 3; ++m) {
        int rr0 = 10 * m;
        asm("" : "+s"(rr0));   // opaque: keep the 3 iterations from re-unrolling
        stage2<0, true, true>(st, cx, rr0 + 0); stage1<0, 0, true, true, true>(st, cx, rr0 + 0);
        stage2<1, true, true>(st, cx, rr0 + 1); stage1<1, 1, true, true, true>(st, cx, rr0 + 1);
        stage2<2, true, true>(st, cx, rr0 + 2); stage1<2, 0, true, true, true>(st, cx, rr0 + 2);
        stage2<3, true, true>(st, cx, rr0 + 3); stage1<3, 1, true, true, true>(st, cx, rr0 + 3);
        stage2<4, true, true>(st, cx, rr0 + 4); stage1<4, 0, true, true, true>(st, cx, rr0 + 4);
        stage2<0, true, true>(st, cx, rr0 + 5); stage1<0, 1, true, true, true>(st, cx, rr0 + 5);
        stage2<1, true, true>(st, cx, rr0 + 6); stage1<1, 0, true, true, true>(st, cx, rr0 + 6);
        stage2<2, true, true>(st, cx, rr0 + 7); stage1<2, 1, true, true, true>(st, cx, rr0 + 7);
        stage2<3, true, true>(st, cx, rr0 + 8); stage1<3, 0, true, true, true>(st, cx, rr0 + 8);
        stage2<4, true, true>(st, cx, rr0 + 9); stage1<4, 1, true, true, true>(st, cx, rr0 + 9);
    }
    // epilogue: stage2 of solve(39); output row yb+31; slot 0 holds raw row 35.
    stage2<0, true, true>(st, cx, 40);
}

}  // namespace

extern "C" void kernel_launch(void* const* d_in, const int* in_sizes, int n_in,
                              void* d_out, int out_size, void* d_ws, size_t ws_size,
                              hipStream_t stream) {
    const float* g  = (const float*)d_in[0];   // guidance [8,3,512,512]
    const float* p  = (const float*)d_in[1];   // input    [8,3,512,512]
    float* out = (float*)d_out;                // [8,3,512,512]

    dim3 grid(WW / OUTW, HH / SR, BN);         // (16, 16, 8) = 2048 single-wave blocks
    dim3 block(64);

    hipLaunchKernelGGL(fused_kernel, grid, block, 0, stream, g, p, out);
}